// Round 3
// baseline (13175.391 us; speedup 1.0000x reference)
//
#include <hip/hip_runtime.h>
#include <stdint.h>

typedef unsigned short u16;
typedef __attribute__((ext_vector_type(4))) float f32x4;
typedef __attribute__((ext_vector_type(8))) short s16x8;
typedef __attribute__((ext_vector_type(4))) u16 u16x4;

__device__ __forceinline__ u16 f2bf(float x) {
  union { float f; uint32_t u; } v; v.f = x;
  uint32_t r = v.u + 0x7FFFu + ((v.u >> 16) & 1u);
  return (u16)(r >> 16);
}
__device__ __forceinline__ float bf2f(u16 b) {
  union { uint32_t u; float f; } v; v.u = ((uint32_t)b) << 16;
  return v.f;
}

__device__ __forceinline__ void gload16(const void* g, const void* l) {
  __builtin_amdgcn_global_load_lds((const __attribute__((address_space(1))) void*)g,
                                   (__attribute__((address_space(3))) void*)l,
                                   16, 0, 0);
}

__global__ void fill_k(float* out, int n, float v) {
  for (int i = blockIdx.x * blockDim.x + threadIdx.x; i < n; i += gridDim.x * blockDim.x)
    out[i] = v;
}

// ---------------- fp32 -> bf16 convert (vectorized) ----------------
__global__ void cvt_k(const float* __restrict__ in, u16* __restrict__ out, int n4) {
  int i = blockIdx.x * blockDim.x + threadIdx.x;
  if (i >= n4) return;
  f32x4 v = ((const f32x4*)in)[i];
  u16x4 o;
  o.x = f2bf(v.x); o.y = f2bf(v.y); o.z = f2bf(v.z); o.w = f2bf(v.w);
  ((u16x4*)out)[i] = o;
}

// ---------------- fp32 -> bf16 hi+lo split ----------------
__global__ void cvt2_k(const float* __restrict__ in, u16* __restrict__ hi,
                       u16* __restrict__ lo, int n4) {
  int i = blockIdx.x * blockDim.x + threadIdx.x;
  if (i >= n4) return;
  f32x4 v = ((const f32x4*)in)[i];
  u16x4 h, l;
#pragma unroll
  for (int j = 0; j < 4; ++j) {
    u16 hb = f2bf(v[j]);
    h[j] = hb;
    l[j] = f2bf(v[j] - bf2f(hb));
  }
  ((u16x4*)hi)[i] = h;
  ((u16x4*)lo)[i] = l;
}

// ------------- fp32 [2048][2048] -> bf16 hi+lo transposed -------------
__global__ void cvtT2_k(const float* __restrict__ in, u16* __restrict__ hi,
                        u16* __restrict__ lo) {
  __shared__ float t[32][33];
  int tx = threadIdx.x, ty = threadIdx.y;
  int c = blockIdx.x * 32 + tx;
#pragma unroll
  for (int j = 0; j < 4; ++j) {
    int r = blockIdx.y * 32 + ty + j * 8;
    t[ty + j * 8][tx] = in[(size_t)r * 2048 + c];
  }
  __syncthreads();
  int c2 = blockIdx.y * 32 + tx;
#pragma unroll
  for (int j = 0; j < 4; ++j) {
    int r2 = blockIdx.x * 32 + ty + j * 8;
    float x = t[tx][ty + j * 8];
    u16 hb = f2bf(x);
    hi[(size_t)r2 * 2048 + c2] = hb;
    lo[(size_t)r2 * 2048 + c2] = f2bf(x - bf2f(hb));
  }
}

// ------------- bf16 GEMM: C = sum_p A_p[M][K] * B_p[N][K]^T  (split-precision passes) ----
// OUTMODE: 0 = fp32, 1 = bf16, 2 = bf16 hi+lo pair (C, C2)
template <typename CT, int OUTMODE, int NP>
__global__ __launch_bounds__(256) void btgemm_k(const u16* __restrict__ A0,
                                                const u16* __restrict__ B0,
                                                const u16* __restrict__ A1,
                                                const u16* __restrict__ B1,
                                                const u16* __restrict__ A2,
                                                const u16* __restrict__ B2,
                                                CT* __restrict__ C,
                                                u16* __restrict__ C2,
                                                int M, int N, int K) {
  __shared__ u16 As[128 * 64];
  __shared__ u16 Bs[128 * 64];
  int nnt = N >> 7;
  int bid = blockIdx.x;
  int nwg = gridDim.x;
  if ((nwg & 7) == 0) { int q = nwg >> 3; bid = (bid & 7) * q + (bid >> 3); }  // XCD swizzle
  int mt = bid / nnt, nt = bid - mt * nnt;
  int tid = threadIdx.x, wave = tid >> 6, lane = tid & 63;
  int l15 = lane & 15, l4 = lane >> 4;
  int wr = wave >> 1, wc = wave & 1;
  int sr = lane >> 3, sc = lane & 7;
  int gsl = (sc ^ sr) * 8;  // pre-swizzled source slot (elements)

  const u16* Alist[3] = {A0, A1, A2};
  const u16* Blist[3] = {B0, B1, B2};
  size_t aoff = (size_t)(mt * 128 + wave * 32 + sr) * K + gsl;
  size_t boff = (size_t)(nt * 128 + wave * 32 + sr) * K + gsl;
  u16* Asw = As + wave * 32 * 64;
  u16* Bsw = Bs + wave * 32 * 64;

  f32x4 acc[4][4];
#pragma unroll
  for (int i = 0; i < 4; ++i)
#pragma unroll
    for (int j = 0; j < 4; ++j) acc[i][j] = f32x4{0.f, 0.f, 0.f, 0.f};

#pragma unroll
  for (int p = 0; p < NP; ++p) {
    const u16* Ag = Alist[p] + aoff;
    const u16* Bg = Blist[p] + boff;
    for (int kt = 0; kt < K; kt += 64) {
#pragma unroll
      for (int i = 0; i < 4; ++i) {
        gload16(Ag + kt + i * 8 * K, Asw + i * 512);
        gload16(Bg + kt + i * 8 * K, Bsw + i * 512);
      }
      __syncthreads();
#pragma unroll
      for (int kk = 0; kk < 2; ++kk) {
        s16x8 af[4], bfr[4];
#pragma unroll
        for (int mf = 0; mf < 4; ++mf) {
          int row = wr * 64 + mf * 16 + l15;
          int sl = ((kk * 4 + l4) ^ (row & 7)) * 8;
          af[mf] = *(const s16x8*)(As + row * 64 + sl);
        }
#pragma unroll
        for (int nf = 0; nf < 4; ++nf) {
          int row = wc * 64 + nf * 16 + l15;
          int sl = ((kk * 4 + l4) ^ (row & 7)) * 8;
          bfr[nf] = *(const s16x8*)(Bs + row * 64 + sl);
        }
#pragma unroll
        for (int mf = 0; mf < 4; ++mf)
#pragma unroll
          for (int nf = 0; nf < 4; ++nf)
            acc[mf][nf] = __builtin_amdgcn_mfma_f32_16x16x32_bf16(af[mf], bfr[nf], acc[mf][nf], 0, 0, 0);
      }
      __syncthreads();
    }
  }

  int crow = mt * 128 + wr * 64 + l4 * 4;
  int ccol = nt * 128 + wc * 64 + l15;
#pragma unroll
  for (int mf = 0; mf < 4; ++mf)
#pragma unroll
    for (int nf = 0; nf < 4; ++nf)
#pragma unroll
      for (int r = 0; r < 4; ++r) {
        size_t idx = (size_t)(crow + mf * 16 + r) * N + (ccol + nf * 16);
        float v = acc[mf][nf][r];
        if constexpr (OUTMODE == 0) {
          C[idx] = v;
        } else if constexpr (OUTMODE == 1) {
          C[idx] = f2bf(v);
        } else {
          u16 hb = f2bf(v);
          C[idx] = hb;
          C2[idx] = f2bf(v - bf2f(hb));
        }
      }
}

// ------------- EXACT fp32 VALU attention (diagnostic bisect of flash attn + vtrans) ----
// qkv: [8192][6144] bf16 token-major. outl: [8192][2048] bf16.
// grid (S/64=32, B*H=64), block 64 (1 wave). Online softmax per lane (= per q-row).
__global__ __launch_bounds__(64) void attn_exact_k(const u16* __restrict__ qkv,
                                                   u16* __restrict__ outl) {
  __shared__ u16 qs[64][130];  // odd 65-word stride -> conflict-free per-lane row reads
  __shared__ u16 ks[64][128];  // broadcast reads only
  __shared__ u16 vs[64][128];  // broadcast reads only

  int qb = blockIdx.x, bh = blockIdx.y;
  int b = bh >> 4, h = bh & 15;
  int lane = threadIdx.x;
  size_t base = (size_t)b * 2048;
  int q0 = qb * 64;

  for (int it = 0; it < 128; ++it) {
    int idx = it * 64 + lane;
    int r = idx >> 7, c = idx & 127;
    qs[r][c] = qkv[(base + q0 + r) * 6144 + h * 128 + c];
  }

  float m = -1e30f, l = 0.f;
  float o[128];
#pragma unroll
  for (int d = 0; d < 128; ++d) o[d] = 0.f;

  const float sc = 0.088388348f;   // 1/sqrt(128)
  const float l2e = 1.4426950409f;

  for (int kt = 0; kt < 32; ++kt) {
    __syncthreads();
    int kv0 = kt * 64;
    for (int it = 0; it < 128; ++it) {
      int idx = it * 64 + lane;
      int r = idx >> 7, c = idx & 127;
      ks[r][c] = qkv[(base + kv0 + r) * 6144 + 2048 + h * 128 + c];
      vs[r][c] = qkv[(base + kv0 + r) * 6144 + 4096 + h * 128 + c];
    }
    __syncthreads();
    for (int kv = 0; kv < 64; ++kv) {
      float s = 0.f;
#pragma unroll 16
      for (int d = 0; d < 128; ++d) s += bf2f(qs[lane][d]) * bf2f(ks[kv][d]);
      s *= sc;
      float mn = fmaxf(m, s);
      float fs = exp2f((m - mn) * l2e);
      float p = exp2f((s - mn) * l2e);
      l = l * fs + p;
      m = mn;
#pragma unroll
      for (int d = 0; d < 128; ++d) o[d] = o[d] * fs + p * bf2f(vs[kv][d]);
    }
  }

  float inv = 1.0f / l;
#pragma unroll
  for (int d = 0; d < 128; ++d)
    outl[(base + q0 + lane) * 2048 + h * 128 + d] = f2bf(o[d] * inv);
}

extern "C" void kernel_launch(void* const* d_in, const int* in_sizes, int n_in,
                              void* d_out, int out_size, void* d_ws, size_t ws_size,
                              hipStream_t stream) {
  (void)in_sizes; (void)n_in;
  const float* hs  = (const float*)d_in[0];
  const float* Wq  = (const float*)d_in[1];
  const float* Wkd = (const float*)d_in[2];
  const float* Wvd = (const float*)d_in[3];
  const float* Wku = (const float*)d_in[4];
  const float* Wo  = (const float*)d_in[5];
  float* out = (float*)d_out;
  char* ws = (char*)d_ws;

  // ws sentinel: need 192 MiB
  if (ws_size < 201326592ull) {
    fill_k<<<4096, 256, 0, stream>>>(out, out_size, 1e9f);
    return;
  }

  // workspace layout (bytes), total 192 MiB, time-multiplexed:
  //  [0,   25.17M) W3 (live: cvt -> qkv GEMM); then WcL at [0, 8.39M)
  //  [25.17M, 33.55M) WcH
  //  [33.55M, 67.11M) hsH (live -> qkv GEMM); then WkuTH|WoH|WkuTL|WoL; then outl
  //  [67.11M, 167.77M) qkv
  //  [167.77M, 201.33M) hsL (live -> qkv GEMM); then (unused this round)
  u16* W3    = (u16*)(ws);
  u16* WcL   = (u16*)(ws);
  u16* WcH   = (u16*)(ws + 25165824);
  u16* hsH   = (u16*)(ws + 33554432);
  u16* WkuTH = (u16*)(ws + 33554432);
  u16* WoH   = (u16*)(ws + 41943040);
  u16* WkuTL = (u16*)(ws + 50331648);
  u16* WoL   = (u16*)(ws + 58720256);
  u16* outl  = (u16*)(ws + 33554432);
  u16* qkv   = (u16*)(ws + 67108864);
  u16* hsL   = (u16*)(ws + 167772160);

  cvt2_k<<<16384, 256, 0, stream>>>(hs, hsH, hsL, 4194304);
  cvt_k<<<4096, 256, 0, stream>>>(Wq, W3, 1048576);
  cvt_k<<<4096, 256, 0, stream>>>(Wkd, W3 + 4194304, 1048576);
  cvt_k<<<4096, 256, 0, stream>>>(Wvd, W3 + 8388608, 1048576);

  // qkv = (hsH + hsL) @ [Wq|Wk_down|Wv_down]^T   (split-A, 2 passes)
  btgemm_k<u16, 1, 2><<<3072, 256, 0, stream>>>(hsH, W3, hsL, W3, nullptr, nullptr,
                                                qkv, nullptr, 8192, 6144, 2048);

  // Wku/Wo splits (region freed by qkv GEMM completion; stream-ordered)
  cvtT2_k<<<dim3(64, 64), dim3(32, 8), 0, stream>>>(Wku, WkuTH, WkuTL);
  cvt2_k<<<4096, 256, 0, stream>>>(Wo, WoH, WoL, 1048576);

  // Wc = Wo @ Wk_up, split both operands (3 passes), output hi+lo pair
  btgemm_k<u16, 2, 3><<<256, 256, 0, stream>>>(WoH, WkuTH, WoL, WkuTH, WoH, WkuTL,
                                               WcH, WcL, 2048, 2048, 2048);

  // EXACT attention (replaces vtrans + flash attn this round; reads V direct from qkv)
  attn_exact_k<<<dim3(32, 64), 64, 0, stream>>>(qkv, outl);

  // out = out_lat @ (WcH + WcL)^T   (split-B, 2 passes, fp32 out)
  btgemm_k<float, 0, 2><<<1024, 256, 0, stream>>>(outl, WcH, outl, WcL, nullptr, nullptr,
                                                  out, nullptr, 8192, 2048, 2048);
}

// Round 4
// 1227.142 us; speedup vs baseline: 10.7366x; 10.7366x over previous
//
#include <hip/hip_runtime.h>
#include <stdint.h>

typedef unsigned short u16;
typedef __attribute__((ext_vector_type(4))) float f32x4;
typedef __attribute__((ext_vector_type(8))) short s16x8;
typedef __attribute__((ext_vector_type(4))) u16 u16x4;

__device__ __forceinline__ u16 f2bf(float x) {
  union { float f; uint32_t u; } v; v.f = x;
  uint32_t r = v.u + 0x7FFFu + ((v.u >> 16) & 1u);
  return (u16)(r >> 16);
}
__device__ __forceinline__ float bf2f(u16 b) {
  union { uint32_t u; float f; } v; v.u = ((uint32_t)b) << 16;
  return v.f;
}

__device__ __forceinline__ void gload16(const void* g, const void* l) {
  __builtin_amdgcn_global_load_lds((const __attribute__((address_space(1))) void*)g,
                                   (__attribute__((address_space(3))) void*)l,
                                   16, 0, 0);
}

__global__ void fill_k(float* out, int n, float v) {
  for (int i = blockIdx.x * blockDim.x + threadIdx.x; i < n; i += gridDim.x * blockDim.x)
    out[i] = v;
}

// ---------------- fp32 -> bf16 convert (vectorized) ----------------
__global__ void cvt_k(const float* __restrict__ in, u16* __restrict__ out, int n4) {
  int i = blockIdx.x * blockDim.x + threadIdx.x;
  if (i >= n4) return;
  f32x4 v = ((const f32x4*)in)[i];
  u16x4 o;
  o.x = f2bf(v.x); o.y = f2bf(v.y); o.z = f2bf(v.z); o.w = f2bf(v.w);
  ((u16x4*)out)[i] = o;
}

// ---------------- fp32 -> bf16 hi+lo split ----------------
__global__ void cvt2_k(const float* __restrict__ in, u16* __restrict__ hi,
                       u16* __restrict__ lo, int n4) {
  int i = blockIdx.x * blockDim.x + threadIdx.x;
  if (i >= n4) return;
  f32x4 v = ((const f32x4*)in)[i];
  u16x4 h, l;
#pragma unroll
  for (int j = 0; j < 4; ++j) {
    u16 hb = f2bf(v[j]);
    h[j] = hb;
    l[j] = f2bf(v[j] - bf2f(hb));
  }
  ((u16x4*)hi)[i] = h;
  ((u16x4*)lo)[i] = l;
}

// ------------- fp32 [2048][2048] -> bf16 hi+lo transposed -------------
__global__ void cvtT2_k(const float* __restrict__ in, u16* __restrict__ hi,
                        u16* __restrict__ lo) {
  __shared__ float t[32][33];
  int tx = threadIdx.x, ty = threadIdx.y;
  int c = blockIdx.x * 32 + tx;
#pragma unroll
  for (int j = 0; j < 4; ++j) {
    int r = blockIdx.y * 32 + ty + j * 8;
    t[ty + j * 8][tx] = in[(size_t)r * 2048 + c];
  }
  __syncthreads();
  int c2 = blockIdx.y * 32 + tx;
#pragma unroll
  for (int j = 0; j < 4; ++j) {
    int r2 = blockIdx.x * 32 + ty + j * 8;
    float x = t[tx][ty + j * 8];
    u16 hb = f2bf(x);
    hi[(size_t)r2 * 2048 + c2] = hb;
    lo[(size_t)r2 * 2048 + c2] = f2bf(x - bf2f(hb));
  }
}

// ------------- per-head V transpose: qkv[:,4096+h*128+dh] -> Vt[bh][dh][s] -------------
__global__ void vtrans_k(const u16* __restrict__ qkv, u16* __restrict__ Vt) {
  __shared__ u16 t[32][34];
  int bh = blockIdx.z; int b = bh >> 4, h = bh & 15;
  int tx = threadIdx.x, ty = threadIdx.y;
  int dh = blockIdx.x * 32 + tx;
#pragma unroll
  for (int j = 0; j < 4; ++j) {
    int s = blockIdx.y * 32 + ty + j * 8;
    t[ty + j * 8][tx] = qkv[(size_t)(b * 2048 + s) * 6144 + 4096 + h * 128 + dh];
  }
  __syncthreads();
  int s2 = blockIdx.y * 32 + tx;
#pragma unroll
  for (int j = 0; j < 4; ++j) {
    int dh2 = blockIdx.x * 32 + ty + j * 8;
    Vt[(size_t)(bh * 128 + dh2) * 2048 + s2] = t[tx][ty + j * 8];
  }
}

// ------------- bf16 GEMM: C = sum_p A_p[M][K] * B_p[N][K]^T  (split-precision passes) ----
// OUTMODE: 0 = fp32, 1 = bf16, 2 = bf16 hi+lo pair (C, C2)
template <typename CT, int OUTMODE, int NP>
__global__ __launch_bounds__(256) void btgemm_k(const u16* __restrict__ A0,
                                                const u16* __restrict__ B0,
                                                const u16* __restrict__ A1,
                                                const u16* __restrict__ B1,
                                                const u16* __restrict__ A2,
                                                const u16* __restrict__ B2,
                                                CT* __restrict__ C,
                                                u16* __restrict__ C2,
                                                int M, int N, int K) {
  __shared__ u16 As[128 * 64];
  __shared__ u16 Bs[128 * 64];
  int nnt = N >> 7;
  int bid = blockIdx.x;
  int nwg = gridDim.x;
  if ((nwg & 7) == 0) { int q = nwg >> 3; bid = (bid & 7) * q + (bid >> 3); }  // XCD swizzle
  int mt = bid / nnt, nt = bid - mt * nnt;
  int tid = threadIdx.x, wave = tid >> 6, lane = tid & 63;
  int l15 = lane & 15, l4 = lane >> 4;
  int wr = wave >> 1, wc = wave & 1;
  int sr = lane >> 3, sc = lane & 7;
  int gsl = (sc ^ sr) * 8;  // pre-swizzled source slot (elements)

  const u16* Alist[3] = {A0, A1, A2};
  const u16* Blist[3] = {B0, B1, B2};
  size_t aoff = (size_t)(mt * 128 + wave * 32 + sr) * K + gsl;
  size_t boff = (size_t)(nt * 128 + wave * 32 + sr) * K + gsl;
  u16* Asw = As + wave * 32 * 64;
  u16* Bsw = Bs + wave * 32 * 64;

  f32x4 acc[4][4];
#pragma unroll
  for (int i = 0; i < 4; ++i)
#pragma unroll
    for (int j = 0; j < 4; ++j) acc[i][j] = f32x4{0.f, 0.f, 0.f, 0.f};

#pragma unroll
  for (int p = 0; p < NP; ++p) {
    const u16* Ag = Alist[p] + aoff;
    const u16* Bg = Blist[p] + boff;
    for (int kt = 0; kt < K; kt += 64) {
#pragma unroll
      for (int i = 0; i < 4; ++i) {
        gload16(Ag + kt + i * 8 * K, Asw + i * 512);
        gload16(Bg + kt + i * 8 * K, Bsw + i * 512);
      }
      __syncthreads();
#pragma unroll
      for (int kk = 0; kk < 2; ++kk) {
        s16x8 af[4], bfr[4];
#pragma unroll
        for (int mf = 0; mf < 4; ++mf) {
          int row = wr * 64 + mf * 16 + l15;
          int sl = ((kk * 4 + l4) ^ (row & 7)) * 8;
          af[mf] = *(const s16x8*)(As + row * 64 + sl);
        }
#pragma unroll
        for (int nf = 0; nf < 4; ++nf) {
          int row = wc * 64 + nf * 16 + l15;
          int sl = ((kk * 4 + l4) ^ (row & 7)) * 8;
          bfr[nf] = *(const s16x8*)(Bs + row * 64 + sl);
        }
#pragma unroll
        for (int mf = 0; mf < 4; ++mf)
#pragma unroll
          for (int nf = 0; nf < 4; ++nf)
            acc[mf][nf] = __builtin_amdgcn_mfma_f32_16x16x32_bf16(af[mf], bfr[nf], acc[mf][nf], 0, 0, 0);
      }
      __syncthreads();
    }
  }

  int crow = mt * 128 + wr * 64 + l4 * 4;
  int ccol = nt * 128 + wc * 64 + l15;
#pragma unroll
  for (int mf = 0; mf < 4; ++mf)
#pragma unroll
    for (int nf = 0; nf < 4; ++nf)
#pragma unroll
      for (int r = 0; r < 4; ++r) {
        size_t idx = (size_t)(crow + mf * 16 + r) * N + (ccol + nf * 16);
        float v = acc[mf][nf][r];
        if constexpr (OUTMODE == 0) {
          C[idx] = v;
        } else if constexpr (OUTMODE == 1) {
          C[idx] = f2bf(v);
        } else {
          u16 hb = f2bf(v);
          C[idx] = hb;
          C2[idx] = f2bf(v - bf2f(hb));
        }
      }
}

// ------------- MFMA flash attention v2: reg-staged LDS (no global_load_lds) -------------
// qkv: [8192][6144] bf16 token-major. Vt: [64][128][2048] bf16. outl: [8192][2048] bf16.
__global__ __launch_bounds__(256) void attn2_k(const u16* __restrict__ qkv,
                                               const u16* __restrict__ Vt,
                                               u16* __restrict__ outl) {
  __shared__ u16 Ks[64 * 128];   // [kv][d], 256B rows, XOR-swizzled 16B slots
  __shared__ u16 Vs[128 * 64];   // [dh][kv], 128B rows, XOR-swizzled
  __shared__ u16 Ps[4][32][72];  // per-wave P tile

  int qb = blockIdx.x, bh = blockIdx.y;
  int b = bh >> 4, h = bh & 15;
  int tid = threadIdx.x, wave = tid >> 6, lane = tid & 63;
  int l15 = lane & 15, l4 = lane >> 4;
  int q0 = qb * 128 + wave * 32;
  const float ksc = 0.12751743f;  // log2(e)/sqrt(128)

  s16x8 qf[2][4];
#pragma unroll
  for (int mf = 0; mf < 2; ++mf)
#pragma unroll
    for (int kf = 0; kf < 4; ++kf)
      qf[mf][kf] = *(const s16x8*)(qkv + (size_t)(b * 2048 + q0 + mf * 16 + l15) * 6144 +
                                   h * 128 + kf * 32 + l4 * 8);

  f32x4 po[2][8];
  float mrun[2][4], lrun[2][4];
#pragma unroll
  for (int mf = 0; mf < 2; ++mf) {
#pragma unroll
    for (int n2 = 0; n2 < 8; ++n2) po[mf][n2] = f32x4{0.f, 0.f, 0.f, 0.f};
#pragma unroll
    for (int r = 0; r < 4; ++r) { mrun[mf][r] = -1e30f; lrun[mf][r] = 0.f; }
  }

  int krow_b = wave * 16;   // wave's K rows: +i*4 + (lane>>4)
  int vrow_b = wave * 32;   // wave's V rows: +i*8 + (lane>>3)
  int kj = lane & 15;       // K 16B slot within row (of 16)
  int vj = lane & 7;        // V 16B slot within row (of 8)

  for (int t = 0; t < 32; ++t) {
    int kv0 = t * 64;
    __syncthreads();  // previous tile's Ks/Vs reads done
    // ---- stage K,V: reg load (unswizzled global) + swizzled ds_write_b128 ----
#pragma unroll
    for (int i = 0; i < 4; ++i) {
      int row = krow_b + i * 4 + (lane >> 4);
      s16x8 kvk = *(const s16x8*)(qkv + (size_t)(b * 2048 + kv0 + row) * 6144 + 2048 +
                                  h * 128 + kj * 8);
      *(s16x8*)(Ks + row * 128 + ((kj ^ (row & 7)) * 8)) = kvk;
      int row2 = vrow_b + i * 8 + (lane >> 3);
      s16x8 vvv = *(const s16x8*)(Vt + (size_t)(bh * 128 + row2) * 2048 + kv0 + vj * 8);
      *(s16x8*)(Vs + row2 * 64 + ((vj ^ (row2 & 7)) * 8)) = vvv;
    }
    __syncthreads();  // staging visible

    // ---- QK^T ----
    f32x4 sa[2][4];
#pragma unroll
    for (int mf = 0; mf < 2; ++mf)
#pragma unroll
      for (int nf = 0; nf < 4; ++nf) sa[mf][nf] = f32x4{0.f, 0.f, 0.f, 0.f};
#pragma unroll
    for (int kf = 0; kf < 4; ++kf) {
      s16x8 kb[4];
#pragma unroll
      for (int nf = 0; nf < 4; ++nf) {
        int row = nf * 16 + l15;
        int sl = ((kf * 4 + l4) ^ (row & 7)) * 8;
        kb[nf] = *(const s16x8*)(Ks + row * 128 + sl);
      }
#pragma unroll
      for (int mf = 0; mf < 2; ++mf)
#pragma unroll
        for (int nf = 0; nf < 4; ++nf)
          sa[mf][nf] = __builtin_amdgcn_mfma_f32_16x16x32_bf16(qf[mf][kf], kb[nf], sa[mf][nf], 0, 0, 0);
    }

    // ---- online softmax (wave-parallel, 16-lane groups) ----
    float fs[2][4];
#pragma unroll
    for (int mf = 0; mf < 2; ++mf) {
      float rmax[4], rsum[4];
#pragma unroll
      for (int r = 0; r < 4; ++r)
        rmax[r] = fmaxf(fmaxf(sa[mf][0][r], sa[mf][1][r]), fmaxf(sa[mf][2][r], sa[mf][3][r]));
#pragma unroll
      for (int d = 1; d < 16; d <<= 1)
#pragma unroll
        for (int r = 0; r < 4; ++r) rmax[r] = fmaxf(rmax[r], __shfl_xor(rmax[r], d, 64));
      u16 pw[4][4];
#pragma unroll
      for (int r = 0; r < 4; ++r) {
        float mnew = fmaxf(mrun[mf][r], rmax[r]);
        fs[mf][r] = exp2f((mrun[mf][r] - mnew) * ksc);
        mrun[mf][r] = mnew;
        rsum[r] = 0.f;
#pragma unroll
        for (int nf = 0; nf < 4; ++nf) {
          float p = exp2f((sa[mf][nf][r] - mnew) * ksc);
          rsum[r] += p;
          pw[nf][r] = f2bf(p);
        }
      }
#pragma unroll
      for (int d = 1; d < 16; d <<= 1)
#pragma unroll
        for (int r = 0; r < 4; ++r) rsum[r] += __shfl_xor(rsum[r], d, 64);
#pragma unroll
      for (int r = 0; r < 4; ++r) lrun[mf][r] = lrun[mf][r] * fs[mf][r] + rsum[r];
#pragma unroll
      for (int nf = 0; nf < 4; ++nf)
#pragma unroll
        for (int r = 0; r < 4; ++r)
          Ps[wave][mf * 16 + l4 * 4 + r][nf * 16 + l15] = pw[nf][r];
    }
    __syncthreads();  // defensive: Ps writes drained (lgkmcnt(0)) before b128 reads

    // rescale O
#pragma unroll
    for (int mf = 0; mf < 2; ++mf)
#pragma unroll
      for (int n2 = 0; n2 < 8; ++n2)
#pragma unroll
        for (int r = 0; r < 4; ++r) po[mf][n2][r] *= fs[mf][r];

    // ---- P fragments ----
    s16x8 pa[2][2];
#pragma unroll
    for (int mf = 0; mf < 2; ++mf)
#pragma unroll
      for (int k2 = 0; k2 < 2; ++k2)
        pa[mf][k2] = *(const s16x8*)&Ps[wave][mf * 16 + l15][k2 * 32 + l4 * 8];

    // ---- PV ----
#pragma unroll
    for (int n2 = 0; n2 < 8; ++n2) {
#pragma unroll
      for (int k2 = 0; k2 < 2; ++k2) {
        int row = n2 * 16 + l15;
        int sl = ((k2 * 4 + l4) ^ (row & 7)) * 8;
        s16x8 vb = *(const s16x8*)(Vs + row * 64 + sl);
#pragma unroll
        for (int mf = 0; mf < 2; ++mf)
          po[mf][n2] = __builtin_amdgcn_mfma_f32_16x16x32_bf16(pa[mf][k2], vb, po[mf][n2], 0, 0, 0);
      }
    }
  }

  // epilogue: normalize + store token-major
#pragma unroll
  for (int mf = 0; mf < 2; ++mf) {
    float inv[4];
#pragma unroll
    for (int r = 0; r < 4; ++r) inv[r] = 1.0f / lrun[mf][r];
#pragma unroll
    for (int n2 = 0; n2 < 8; ++n2)
#pragma unroll
      for (int r = 0; r < 4; ++r)
        outl[(size_t)(b * 2048 + q0 + mf * 16 + l4 * 4 + r) * 2048 + h * 128 + n2 * 16 + l15] =
            f2bf(po[mf][n2][r] * inv[r]);
  }
}

extern "C" void kernel_launch(void* const* d_in, const int* in_sizes, int n_in,
                              void* d_out, int out_size, void* d_ws, size_t ws_size,
                              hipStream_t stream) {
  (void)in_sizes; (void)n_in;
  const float* hs  = (const float*)d_in[0];
  const float* Wq  = (const float*)d_in[1];
  const float* Wkd = (const float*)d_in[2];
  const float* Wvd = (const float*)d_in[3];
  const float* Wku = (const float*)d_in[4];
  const float* Wo  = (const float*)d_in[5];
  float* out = (float*)d_out;
  char* ws = (char*)d_ws;

  // ws sentinel: need 192 MiB
  if (ws_size < 201326592ull) {
    fill_k<<<4096, 256, 0, stream>>>(out, out_size, 1e9f);
    return;
  }

  // workspace layout (bytes), total 192 MiB, time-multiplexed:
  //  [0,   25.17M) W3 (live: cvt -> qkv GEMM); then WcL at [0, 8.39M)
  //  [25.17M, 33.55M) WcH
  //  [33.55M, 67.11M) hsH (live -> qkv GEMM); then WkuTH|WoH|WkuTL|WoL; then outl
  //  [67.11M, 167.77M) qkv
  //  [167.77M, 201.33M) hsL (live -> qkv GEMM); then Vt
  u16* W3    = (u16*)(ws);
  u16* WcL   = (u16*)(ws);
  u16* WcH   = (u16*)(ws + 25165824);
  u16* hsH   = (u16*)(ws + 33554432);
  u16* WkuTH = (u16*)(ws + 33554432);
  u16* WoH   = (u16*)(ws + 41943040);
  u16* WkuTL = (u16*)(ws + 50331648);
  u16* WoL   = (u16*)(ws + 58720256);
  u16* outl  = (u16*)(ws + 33554432);
  u16* qkv   = (u16*)(ws + 67108864);
  u16* hsL   = (u16*)(ws + 167772160);
  u16* Vt    = (u16*)(ws + 167772160);

  cvt2_k<<<16384, 256, 0, stream>>>(hs, hsH, hsL, 4194304);
  cvt_k<<<4096, 256, 0, stream>>>(Wq, W3, 1048576);
  cvt_k<<<4096, 256, 0, stream>>>(Wkd, W3 + 4194304, 1048576);
  cvt_k<<<4096, 256, 0, stream>>>(Wvd, W3 + 8388608, 1048576);

  // qkv = (hsH + hsL) @ [Wq|Wk_down|Wv_down]^T   (split-A, 2 passes)
  btgemm_k<u16, 1, 2><<<3072, 256, 0, stream>>>(hsH, W3, hsL, W3, nullptr, nullptr,
                                                qkv, nullptr, 8192, 6144, 2048);

  // Wku/Wo splits (region freed by qkv GEMM completion; stream-ordered)
  cvtT2_k<<<dim3(64, 64), dim3(32, 8), 0, stream>>>(Wku, WkuTH, WkuTL);
  cvt2_k<<<4096, 256, 0, stream>>>(Wo, WoH, WoL, 1048576);

  // Wc = Wo @ Wk_up, split both operands (3 passes), output hi+lo pair
  btgemm_k<u16, 2, 3><<<256, 256, 0, stream>>>(WoH, WkuTH, WoL, WkuTH, WoH, WkuTL,
                                               WcH, WcL, 2048, 2048, 2048);

  vtrans_k<<<dim3(4, 64, 64), dim3(32, 8), 0, stream>>>(qkv, Vt);
  attn2_k<<<dim3(16, 64), 256, 0, stream>>>(qkv, Vt, outl);

  // out = out_lat @ (WcH + WcL)^T   (split-B, 2 passes, fp32 out)
  btgemm_k<float, 0, 2><<<1024, 256, 0, stream>>>(outl, WcH, outl, WcL, nullptr, nullptr,
                                                  out, nullptr, 8192, 2048, 2048);
}

// Round 5
// 938.109 us; speedup vs baseline: 14.0446x; 1.3081x over previous
//
#include <hip/hip_runtime.h>
#include <stdint.h>

typedef unsigned short u16;
typedef __attribute__((ext_vector_type(4))) float f32x4;
typedef __attribute__((ext_vector_type(8))) short s16x8;
typedef __attribute__((ext_vector_type(4))) u16 u16x4;

__device__ __forceinline__ u16 f2bf(float x) {
  union { float f; uint32_t u; } v; v.f = x;
  uint32_t r = v.u + 0x7FFFu + ((v.u >> 16) & 1u);
  return (u16)(r >> 16);
}
__device__ __forceinline__ float bf2f(u16 b) {
  union { uint32_t u; float f; } v; v.u = ((uint32_t)b) << 16;
  return v.f;
}

__device__ __forceinline__ void gload16(const void* g, const void* l) {
  __builtin_amdgcn_global_load_lds((const __attribute__((address_space(1))) void*)g,
                                   (__attribute__((address_space(3))) void*)l,
                                   16, 0, 0);
}

__global__ void fill_k(float* out, int n, float v) {
  for (int i = blockIdx.x * blockDim.x + threadIdx.x; i < n; i += gridDim.x * blockDim.x)
    out[i] = v;
}

// ---------------- fp32 -> bf16 convert (vectorized) ----------------
__global__ void cvt_k(const float* __restrict__ in, u16* __restrict__ out, int n4) {
  int i = blockIdx.x * blockDim.x + threadIdx.x;
  if (i >= n4) return;
  f32x4 v = ((const f32x4*)in)[i];
  u16x4 o;
  o.x = f2bf(v.x); o.y = f2bf(v.y); o.z = f2bf(v.z); o.w = f2bf(v.w);
  ((u16x4*)out)[i] = o;
}

// ---------------- fp32 -> bf16 hi+lo split ----------------
__global__ void cvt2_k(const float* __restrict__ in, u16* __restrict__ hi,
                       u16* __restrict__ lo, int n4) {
  int i = blockIdx.x * blockDim.x + threadIdx.x;
  if (i >= n4) return;
  f32x4 v = ((const f32x4*)in)[i];
  u16x4 h, l;
#pragma unroll
  for (int j = 0; j < 4; ++j) {
    u16 hb = f2bf(v[j]);
    h[j] = hb;
    l[j] = f2bf(v[j] - bf2f(hb));
  }
  ((u16x4*)hi)[i] = h;
  ((u16x4*)lo)[i] = l;
}

// ------------- fp32 [2048][2048] -> bf16 transposed -------------
__global__ void cvtT_k(const float* __restrict__ in, u16* __restrict__ out) {
  __shared__ float t[32][33];
  int tx = threadIdx.x, ty = threadIdx.y;
  int c = blockIdx.x * 32 + tx;
#pragma unroll
  for (int j = 0; j < 4; ++j) {
    int r = blockIdx.y * 32 + ty + j * 8;
    t[ty + j * 8][tx] = in[(size_t)r * 2048 + c];
  }
  __syncthreads();
  int c2 = blockIdx.y * 32 + tx;
#pragma unroll
  for (int j = 0; j < 4; ++j) {
    int r2 = blockIdx.x * 32 + ty + j * 8;
    out[(size_t)r2 * 2048 + c2] = f2bf(t[tx][ty + j * 8]);
  }
}

// ------------- per-head V transpose: qkv[:,4096+h*128+dh] -> Vt[bh][dh][s] -------------
__global__ void vtrans_k(const u16* __restrict__ qkv, u16* __restrict__ Vt) {
  __shared__ u16 t[32][34];
  int bh = blockIdx.z; int b = bh >> 4, h = bh & 15;
  int tx = threadIdx.x, ty = threadIdx.y;
  int dh = blockIdx.x * 32 + tx;
#pragma unroll
  for (int j = 0; j < 4; ++j) {
    int s = blockIdx.y * 32 + ty + j * 8;
    t[ty + j * 8][tx] = qkv[(size_t)(b * 2048 + s) * 6144 + 4096 + h * 128 + dh];
  }
  __syncthreads();
  int s2 = blockIdx.y * 32 + tx;
#pragma unroll
  for (int j = 0; j < 4; ++j) {
    int dh2 = blockIdx.x * 32 + ty + j * 8;
    Vt[(size_t)(bh * 128 + dh2) * 2048 + s2] = t[tx][ty + j * 8];
  }
}

// ------------- bf16 GEMM: C = sum_p A_p[M][K] * B_p[N][K]^T  (split-precision passes) ----
// OUTMODE: 0 = fp32, 1 = bf16, 2 = bf16 hi+lo pair (C, C2)
template <typename CT, int OUTMODE, int NP>
__global__ __launch_bounds__(256) void btgemm_k(const u16* __restrict__ A0,
                                                const u16* __restrict__ B0,
                                                const u16* __restrict__ A1,
                                                const u16* __restrict__ B1,
                                                CT* __restrict__ C,
                                                u16* __restrict__ C2,
                                                int M, int N, int K) {
  __shared__ u16 As[128 * 64];
  __shared__ u16 Bs[128 * 64];
  int nnt = N >> 7;
  int bid = blockIdx.x;
  int nwg = gridDim.x;
  if ((nwg & 7) == 0) { int q = nwg >> 3; bid = (bid & 7) * q + (bid >> 3); }  // XCD swizzle
  int mt = bid / nnt, nt = bid - mt * nnt;
  int tid = threadIdx.x, wave = tid >> 6, lane = tid & 63;
  int l15 = lane & 15, l4 = lane >> 4;
  int wr = wave >> 1, wc = wave & 1;
  int sr = lane >> 3, sc = lane & 7;
  int gsl = (sc ^ sr) * 8;  // pre-swizzled source slot (elements)

  const u16* Alist[2] = {A0, A1};
  const u16* Blist[2] = {B0, B1};
  size_t aoff = (size_t)(mt * 128 + wave * 32 + sr) * K + gsl;
  size_t boff = (size_t)(nt * 128 + wave * 32 + sr) * K + gsl;
  u16* Asw = As + wave * 32 * 64;
  u16* Bsw = Bs + wave * 32 * 64;

  f32x4 acc[4][4];
#pragma unroll
  for (int i = 0; i < 4; ++i)
#pragma unroll
    for (int j = 0; j < 4; ++j) acc[i][j] = f32x4{0.f, 0.f, 0.f, 0.f};

#pragma unroll
  for (int p = 0; p < NP; ++p) {
    const u16* Ag = Alist[p] + aoff;
    const u16* Bg = Blist[p] + boff;
    for (int kt = 0; kt < K; kt += 64) {
#pragma unroll
      for (int i = 0; i < 4; ++i) {
        gload16(Ag + kt + i * 8 * K, Asw + i * 512);
        gload16(Bg + kt + i * 8 * K, Bsw + i * 512);
      }
      __syncthreads();
#pragma unroll
      for (int kk = 0; kk < 2; ++kk) {
        s16x8 af[4], bfr[4];
#pragma unroll
        for (int mf = 0; mf < 4; ++mf) {
          int row = wr * 64 + mf * 16 + l15;
          int sl = ((kk * 4 + l4) ^ (row & 7)) * 8;
          af[mf] = *(const s16x8*)(As + row * 64 + sl);
        }
#pragma unroll
        for (int nf = 0; nf < 4; ++nf) {
          int row = wc * 64 + nf * 16 + l15;
          int sl = ((kk * 4 + l4) ^ (row & 7)) * 8;
          bfr[nf] = *(const s16x8*)(Bs + row * 64 + sl);
        }
#pragma unroll
        for (int mf = 0; mf < 4; ++mf)
#pragma unroll
          for (int nf = 0; nf < 4; ++nf)
            acc[mf][nf] = __builtin_amdgcn_mfma_f32_16x16x32_bf16(af[mf], bfr[nf], acc[mf][nf], 0, 0, 0);
      }
      __syncthreads();
    }
  }

  int crow = mt * 128 + wr * 64 + l4 * 4;
  int ccol = nt * 128 + wc * 64 + l15;
#pragma unroll
  for (int mf = 0; mf < 4; ++mf)
#pragma unroll
    for (int nf = 0; nf < 4; ++nf)
#pragma unroll
      for (int r = 0; r < 4; ++r) {
        size_t idx = (size_t)(crow + mf * 16 + r) * N + (ccol + nf * 16);
        float v = acc[mf][nf][r];
        if constexpr (OUTMODE == 0) {
          C[idx] = v;
        } else if constexpr (OUTMODE == 1) {
          C[idx] = f2bf(v);
        } else {
          u16 hb = f2bf(v);
          C[idx] = hb;
          C2[idx] = f2bf(v - bf2f(hb));
        }
      }
}

// ------------- MFMA flash attention v3: reg-staged + T14 async-stage + setprio -------------
// qkv: [8192][6144] bf16 token-major. Vt: [64][128][2048] bf16. outl: [8192][2048] bf16.
__global__ __launch_bounds__(256) void attn3_k(const u16* __restrict__ qkv,
                                               const u16* __restrict__ Vt,
                                               u16* __restrict__ outl) {
  __shared__ u16 Ks[64 * 128];   // [kv][d], 256B rows, XOR-swizzled 16B slots
  __shared__ u16 Vs[128 * 64];   // [dh][kv], 128B rows, XOR-swizzled
  __shared__ u16 Ps[4][32][72];  // per-wave P tile

  int qb = blockIdx.x, bh = blockIdx.y;
  int b = bh >> 4, h = bh & 15;
  int tid = threadIdx.x, wave = tid >> 6, lane = tid & 63;
  int l15 = lane & 15, l4 = lane >> 4;
  int q0 = qb * 128 + wave * 32;
  const float ksc = 0.12751743f;  // log2(e)/sqrt(128)

  s16x8 qf[2][4];
#pragma unroll
  for (int mf = 0; mf < 2; ++mf)
#pragma unroll
    for (int kf = 0; kf < 4; ++kf)
      qf[mf][kf] = *(const s16x8*)(qkv + (size_t)(b * 2048 + q0 + mf * 16 + l15) * 6144 +
                                   h * 128 + kf * 32 + l4 * 8);

  f32x4 po[2][8];
  float mrun[2][4], lrun[2][4];
#pragma unroll
  for (int mf = 0; mf < 2; ++mf) {
#pragma unroll
    for (int n2 = 0; n2 < 8; ++n2) po[mf][n2] = f32x4{0.f, 0.f, 0.f, 0.f};
#pragma unroll
    for (int r = 0; r < 4; ++r) { mrun[mf][r] = -1e30f; lrun[mf][r] = 0.f; }
  }

  int krow_b = wave * 16;   // wave's K rows: +i*4 + (lane>>4)
  int vrow_b = wave * 32;   // wave's V rows: +i*8 + (lane>>3)
  int kj = lane & 15;       // K 16B slot within row (of 16)
  int vj = lane & 7;        // V 16B slot within row (of 8)

  s16x8 kr[4], vr[4];       // T14: in-flight next tile
#define GLOAD_TILE(kv0)                                                                  \
  _Pragma("unroll") for (int i = 0; i < 4; ++i) {                                        \
    int row = krow_b + i * 4 + (lane >> 4);                                              \
    kr[i] = *(const s16x8*)(qkv + (size_t)(b * 2048 + (kv0) + row) * 6144 + 2048 +       \
                            h * 128 + kj * 8);                                           \
    int row2 = vrow_b + i * 8 + (lane >> 3);                                             \
    vr[i] = *(const s16x8*)(Vt + (size_t)(bh * 128 + row2) * 2048 + (kv0) + vj * 8);     \
  }

  GLOAD_TILE(0)

  for (int t = 0; t < 32; ++t) {
    __syncthreads();  // previous tile's Ks/Vs reads done
    // ---- write staged regs to LDS (swizzled) ----
#pragma unroll
    for (int i = 0; i < 4; ++i) {
      int row = krow_b + i * 4 + (lane >> 4);
      *(s16x8*)(Ks + row * 128 + ((kj ^ (row & 7)) * 8)) = kr[i];
      int row2 = vrow_b + i * 8 + (lane >> 3);
      *(s16x8*)(Vs + row2 * 64 + ((vj ^ (row2 & 7)) * 8)) = vr[i];
    }
    __syncthreads();  // staging visible
    // ---- issue next tile's global loads; land during compute ----
    if (t < 31) GLOAD_TILE((t + 1) * 64)

    // ---- QK^T ----
    f32x4 sa[2][4];
#pragma unroll
    for (int mf = 0; mf < 2; ++mf)
#pragma unroll
      for (int nf = 0; nf < 4; ++nf) sa[mf][nf] = f32x4{0.f, 0.f, 0.f, 0.f};
    __builtin_amdgcn_s_setprio(1);
#pragma unroll
    for (int kf = 0; kf < 4; ++kf) {
      s16x8 kb[4];
#pragma unroll
      for (int nf = 0; nf < 4; ++nf) {
        int row = nf * 16 + l15;
        int sl = ((kf * 4 + l4) ^ (row & 7)) * 8;
        kb[nf] = *(const s16x8*)(Ks + row * 128 + sl);
      }
#pragma unroll
      for (int mf = 0; mf < 2; ++mf)
#pragma unroll
        for (int nf = 0; nf < 4; ++nf)
          sa[mf][nf] = __builtin_amdgcn_mfma_f32_16x16x32_bf16(qf[mf][kf], kb[nf], sa[mf][nf], 0, 0, 0);
    }
    __builtin_amdgcn_s_setprio(0);

    // ---- online softmax (wave-parallel, 16-lane groups) ----
    float fs[2][4];
#pragma unroll
    for (int mf = 0; mf < 2; ++mf) {
      float rmax[4], rsum[4];
#pragma unroll
      for (int r = 0; r < 4; ++r)
        rmax[r] = fmaxf(fmaxf(sa[mf][0][r], sa[mf][1][r]), fmaxf(sa[mf][2][r], sa[mf][3][r]));
#pragma unroll
      for (int d = 1; d < 16; d <<= 1)
#pragma unroll
        for (int r = 0; r < 4; ++r) rmax[r] = fmaxf(rmax[r], __shfl_xor(rmax[r], d, 64));
      u16 pw[4][4];
#pragma unroll
      for (int r = 0; r < 4; ++r) {
        float mnew = fmaxf(mrun[mf][r], rmax[r]);
        fs[mf][r] = exp2f((mrun[mf][r] - mnew) * ksc);
        mrun[mf][r] = mnew;
        rsum[r] = 0.f;
#pragma unroll
        for (int nf = 0; nf < 4; ++nf) {
          float p = exp2f((sa[mf][nf][r] - mnew) * ksc);
          rsum[r] += p;
          pw[nf][r] = f2bf(p);
        }
      }
#pragma unroll
      for (int d = 1; d < 16; d <<= 1)
#pragma unroll
        for (int r = 0; r < 4; ++r) rsum[r] += __shfl_xor(rsum[r], d, 64);
#pragma unroll
      for (int r = 0; r < 4; ++r) lrun[mf][r] = lrun[mf][r] * fs[mf][r] + rsum[r];
#pragma unroll
      for (int nf = 0; nf < 4; ++nf)
#pragma unroll
        for (int r = 0; r < 4; ++r)
          Ps[wave][mf * 16 + l4 * 4 + r][nf * 16 + l15] = pw[nf][r];
    }
    // NOTE: no barrier needed — Ps is per-wave; LDS ops are in-order within a wave.

    // rescale O
#pragma unroll
    for (int mf = 0; mf < 2; ++mf)
#pragma unroll
      for (int n2 = 0; n2 < 8; ++n2)
#pragma unroll
        for (int r = 0; r < 4; ++r) po[mf][n2][r] *= fs[mf][r];

    // ---- P fragments ----
    s16x8 pa[2][2];
#pragma unroll
    for (int mf = 0; mf < 2; ++mf)
#pragma unroll
      for (int k2 = 0; k2 < 2; ++k2)
        pa[mf][k2] = *(const s16x8*)&Ps[wave][mf * 16 + l15][k2 * 32 + l4 * 8];

    // ---- PV ----
    __builtin_amdgcn_s_setprio(1);
#pragma unroll
    for (int n2 = 0; n2 < 8; ++n2) {
#pragma unroll
      for (int k2 = 0; k2 < 2; ++k2) {
        int row = n2 * 16 + l15;
        int sl = ((k2 * 4 + l4) ^ (row & 7)) * 8;
        s16x8 vb = *(const s16x8*)(Vs + row * 64 + sl);
#pragma unroll
        for (int mf = 0; mf < 2; ++mf)
          po[mf][n2] = __builtin_amdgcn_mfma_f32_16x16x32_bf16(pa[mf][k2], vb, po[mf][n2], 0, 0, 0);
      }
    }
    __builtin_amdgcn_s_setprio(0);
  }
#undef GLOAD_TILE

  // epilogue: normalize + store token-major
#pragma unroll
  for (int mf = 0; mf < 2; ++mf) {
    float inv[4];
#pragma unroll
    for (int r = 0; r < 4; ++r) inv[r] = 1.0f / lrun[mf][r];
#pragma unroll
    for (int n2 = 0; n2 < 8; ++n2)
#pragma unroll
      for (int r = 0; r < 4; ++r)
        outl[(size_t)(b * 2048 + q0 + mf * 16 + l4 * 4 + r) * 2048 + h * 128 + n2 * 16 + l15] =
            f2bf(po[mf][n2][r] * inv[r]);
  }
}

extern "C" void kernel_launch(void* const* d_in, const int* in_sizes, int n_in,
                              void* d_out, int out_size, void* d_ws, size_t ws_size,
                              hipStream_t stream) {
  (void)in_sizes; (void)n_in;
  const float* hs  = (const float*)d_in[0];
  const float* Wq  = (const float*)d_in[1];
  const float* Wkd = (const float*)d_in[2];
  const float* Wvd = (const float*)d_in[3];
  const float* Wku = (const float*)d_in[4];
  const float* Wo  = (const float*)d_in[5];
  float* out = (float*)d_out;
  char* ws = (char*)d_ws;

  // ws sentinel: need 192 MiB
  if (ws_size < 201326592ull) {
    fill_k<<<4096, 256, 0, stream>>>(out, out_size, 1e9f);
    return;
  }

  // workspace layout (bytes), total 192 MiB, time-multiplexed:
  //  [0,   25.17M) W3 (live -> qkv GEMM); then WcL at [0, 8.39M)
  //  [25.17M, 33.55M) WcH
  //  [33.55M, 50.33M) hsB (live -> qkv GEMM)
  //  [41.94M, 67.11M) WkuT|WoH|WoL (live after qkv GEMM -> Wc GEMM)
  //  [33.55M, 67.11M) outl (after Wc GEMM)
  //  [67.11M, 167.77M) qkv
  //  [167.77M, 201.33M) Vt
  u16* W3   = (u16*)(ws);
  u16* WcL  = (u16*)(ws);
  u16* WcH  = (u16*)(ws + 25165824);
  u16* hsB  = (u16*)(ws + 33554432);
  u16* WkuT = (u16*)(ws + 41943040);
  u16* WoH  = (u16*)(ws + 50331648);
  u16* WoL  = (u16*)(ws + 58720256);
  u16* outl = (u16*)(ws + 33554432);
  u16* qkv  = (u16*)(ws + 67108864);
  u16* Vt   = (u16*)(ws + 167772160);

  cvt_k<<<16384, 256, 0, stream>>>(hs, hsB, 4194304);
  cvt_k<<<4096, 256, 0, stream>>>(Wq, W3, 1048576);
  cvt_k<<<4096, 256, 0, stream>>>(Wkd, W3 + 4194304, 1048576);
  cvt_k<<<4096, 256, 0, stream>>>(Wvd, W3 + 8388608, 1048576);

  // qkv = hsB @ [Wq|Wk_down|Wv_down]^T   (single pass now)
  btgemm_k<u16, 1, 1><<<3072, 256, 0, stream>>>(hsB, W3, nullptr, nullptr,
                                                qkv, nullptr, 8192, 6144, 2048);

  // Wku/Wo (regions freed by qkv GEMM completion; stream-ordered)
  cvtT_k<<<dim3(64, 64), dim3(32, 8), 0, stream>>>(Wku, WkuT);
  cvt2_k<<<4096, 256, 0, stream>>>(Wo, WoH, WoL, 1048576);

  // Wc = (WoH + WoL) @ WkuT^T   (2 passes), output hi+lo pair
  btgemm_k<u16, 2, 2><<<256, 256, 0, stream>>>(WoH, WkuT, WoL, WkuT,
                                               WcH, WcL, 2048, 2048, 2048);

  vtrans_k<<<dim3(4, 64, 64), dim3(32, 8), 0, stream>>>(qkv, Vt);
  attn3_k<<<dim3(16, 64), 256, 0, stream>>>(qkv, Vt, outl);

  // out = out_lat @ (WcH + WcL)^T   (split-B, 2 passes, fp32 out)
  btgemm_k<float, 0, 2><<<1024, 256, 0, stream>>>(outl, WcH, outl, WcL,
                                                  out, nullptr, 8192, 2048, 2048);
}